// Round 1
// baseline (1276.996 us; speedup 1.0000x reference)
//
#include <hip/hip_runtime.h>

// Problem: B=2, N=120000, T=600000 (derived from in_sizes at launch).
// Outputs flat in d_out (float32): losses[4] | pts[B*T*6*3] | mask[B*T*6]

#define NPART 8192  // loss partial slots per loss term

__device__ inline double waveReduce(double v) {
    #pragma unroll
    for (int off = 32; off > 0; off >>= 1) v += __shfl_down(v, off);
    return v;
}

__global__ __launch_bounds__(256) void mean_kernel(
    const float* __restrict__ pred, double* __restrict__ msum, int N)
{
    const int b = blockIdx.y;
    const float4* p = (const float4*)pred + (size_t)b * N;
    double s0 = 0, s1 = 0, s2 = 0, s3 = 0;
    for (int n = blockIdx.x * blockDim.x + threadIdx.x; n < N;
         n += gridDim.x * blockDim.x) {
        float4 v = p[n];
        s0 += v.x; s1 += v.y; s2 += v.z; s3 += v.w;
    }
    s0 = waveReduce(s0); s1 = waveReduce(s1);
    s2 = waveReduce(s2); s3 = waveReduce(s3);
    if ((threadIdx.x & 63) == 0) {
        atomicAdd(&msum[b * 4 + 0], s0);
        atomicAdd(&msum[b * 4 + 1], s1);
        atomicAdd(&msum[b * 4 + 2], s2);
        atomicAdd(&msum[b * 4 + 3], s3);
    }
}

__global__ __launch_bounds__(256) void tetra_kernel(
    const float* __restrict__ pred, const int* __restrict__ tetra,
    const double* __restrict__ msum,
    float* __restrict__ term, int* __restrict__ deg,
    double* __restrict__ l2p, double* __restrict__ l3p,
    float* __restrict__ out, int N, int T, int B)
{
    // LDS staging: pts padded stride 19 (18 used), mask stride 7 (6 used)
    __shared__ float lds_pts[256 * 19];
    __shared__ float lds_msk[256 * 7];
    __shared__ double sr[2][4];

    const int b = blockIdx.y;
    const int tbase = blockIdx.x * 256;
    const int t = tbase + threadIdx.x;

    float m0 = (float)(msum[b * 4 + 0] / N);
    float m1 = (float)(msum[b * 4 + 1] / N);
    float m2 = (float)(msum[b * 4 + 2] / N);
    float m3 = (float)(msum[b * 4 + 3] / N);

    double l2 = 0.0, l3 = 0.0;

    if (t < T) {
        int4 q4 = ((const int4*)tetra)[(size_t)b * T + t];
        int vi[4] = {q4.x, q4.y, q4.z, q4.w};
        float4 v[4];
        #pragma unroll
        for (int s = 0; s < 4; s++) {
            float4 p = ((const float4*)pred)[(size_t)b * N + vi[s]];
            v[s] = make_float4(p.x - m0, p.y - m1, p.z - m2, p.w - m3);
        }
        float4 vs = make_float4(v[0].x + v[1].x + v[2].x + v[3].x,
                                v[0].y + v[1].y + v[2].y + v[3].y,
                                v[0].z + v[1].z + v[2].z + v[3].z,
                                v[0].w + v[1].w + v[2].w + v[3].w);
        #pragma unroll
        for (int s = 0; s < 4; s++) {
            int base = (b * N + vi[s]) * 4;
            atomicAdd(&term[base + 0], vs.x - 4.0f * v[s].x);
            atomicAdd(&term[base + 1], vs.y - 4.0f * v[s].y);
            atomicAdd(&term[base + 2], vs.z - 4.0f * v[s].z);
            atomicAdd(&term[base + 3], vs.w - 4.0f * v[s].w);
            atomicAdd(&deg[b * N + vi[s]], 1);
        }
        const int EA[6] = {0, 0, 0, 1, 1, 2};
        const int EB[6] = {1, 2, 3, 2, 3, 3};
        #pragma unroll
        for (int e = 0; e < 6; e++) {
            float4 pa = v[EA[e]], pb = v[EB[e]];
            float wa = pa.w, wb = pb.w;
            float edge = wa * wb;
            float dx = pa.x - pb.x, dy = pa.y - pb.y;
            float dz = pa.z - pb.z, dw = pa.w - pb.w;
            l2 += (double)edge;
            float nr = sqrtf(dx * dx + dy * dy + dz * dz + dw * dw) - 0.4f;
            l3 += (double)(nr * nr);
            float sq = (fabsf(dw) > 1e-12f) ? dw : 1.0f;
            float tt = (0.0f - wa) / sq;
            bool msk = edge < 0.0f;
            lds_pts[threadIdx.x * 19 + e * 3 + 0] = msk ? (pa.x + tt * dx) : 0.0f;
            lds_pts[threadIdx.x * 19 + e * 3 + 1] = msk ? (pa.y + tt * dy) : 0.0f;
            lds_pts[threadIdx.x * 19 + e * 3 + 2] = msk ? (pa.z + tt * dz) : 0.0f;
            lds_msk[threadIdx.x * 7 + e] = msk ? 1.0f : 0.0f;
        }
    }
    __syncthreads();

    const int nv = min(256, T - tbase);
    // coalesced pts write: out offset 4 + (b*T + t)*18 + e*3 + k
    size_t pbase = 4 + ((size_t)b * T + tbase) * 18;
    for (int i = threadIdx.x; i < nv * 18; i += 256) {
        int ts = i / 18, j = i - ts * 18;
        out[pbase + i] = lds_pts[ts * 19 + j];
    }
    size_t mbase = 4 + (size_t)B * T * 18 + ((size_t)b * T + tbase) * 6;
    for (int i = threadIdx.x; i < nv * 6; i += 256) {
        int ts = i / 6, j = i - ts * 6;
        out[mbase + i] = lds_msk[ts * 7 + j];
    }

    // block-reduce L2/L3 into per-block partials (no atomics)
    l2 = waveReduce(l2); l3 = waveReduce(l3);
    int wv = threadIdx.x >> 6;
    if ((threadIdx.x & 63) == 0) { sr[0][wv] = l2; sr[1][wv] = l3; }
    __syncthreads();
    if (threadIdx.x == 0) {
        double a = 0, c = 0;
        #pragma unroll
        for (int w = 0; w < 4; w++) { a += sr[0][w]; c += sr[1][w]; }
        int blk = blockIdx.y * gridDim.x + blockIdx.x;
        l2p[blk] = a;
        l3p[blk] = c;
    }
}

__global__ __launch_bounds__(256) void l1_kernel(
    const float* __restrict__ term, const int* __restrict__ deg,
    double* __restrict__ l1p, int BN)
{
    int i = blockIdx.x * 256 + threadIdx.x;
    double s = 0.0;
    if (i < BN) {
        float4 tv = ((const float4*)term)[i];
        float dn = fmaxf(3.0f * (float)deg[i], 1.0f);
        float a = tv.x / dn, b = tv.y / dn, c = tv.z / dn, d = tv.w / dn;
        s = (double)(a * a) + (double)(b * b) + (double)(c * c) + (double)(d * d);
    }
    s = waveReduce(s);
    __shared__ double sr[4];
    int wv = threadIdx.x >> 6;
    if ((threadIdx.x & 63) == 0) sr[wv] = s;
    __syncthreads();
    if (threadIdx.x == 0) {
        double a = 0;
        #pragma unroll
        for (int w = 0; w < 4; w++) a += sr[w];
        l1p[blockIdx.x] = a;
    }
}

__global__ __launch_bounds__(256) void finalize_kernel(
    const double* __restrict__ l1p, const double* __restrict__ l2p,
    const double* __restrict__ l3p, float* __restrict__ out,
    double nd1, double nd23)
{
    double s1 = 0, s2 = 0, s3 = 0;
    for (int i = threadIdx.x; i < NPART; i += 256) {
        s1 += l1p[i]; s2 += l2p[i]; s3 += l3p[i];
    }
    s1 = waveReduce(s1); s2 = waveReduce(s2); s3 = waveReduce(s3);
    __shared__ double sr[3][4];
    int wv = threadIdx.x >> 6;
    if ((threadIdx.x & 63) == 0) { sr[0][wv] = s1; sr[1][wv] = s2; sr[2][wv] = s3; }
    __syncthreads();
    if (threadIdx.x == 0) {
        double a = 0, b = 0, c = 0;
        #pragma unroll
        for (int w = 0; w < 4; w++) { a += sr[0][w]; b += sr[1][w]; c += sr[2][w]; }
        out[0] = (float)(a / nd1);
        out[1] = (float)(b / nd23);
        out[2] = (float)(c / nd23);
        out[3] = 0.0f;
    }
}

extern "C" void kernel_launch(void* const* d_in, const int* in_sizes, int n_in,
                              void* d_out, int out_size, void* d_ws, size_t ws_size,
                              hipStream_t stream) {
    const float* pred = (const float*)d_in[0];
    const int* tetra = (const int*)d_in[1];
    float* out = (float*)d_out;

    const int B = 2;
    const int N = in_sizes[0] / (B * 4);   // 120000
    const int T = in_sizes[1] / (B * 4);   // 600000

    // workspace layout
    char* ws = (char*)d_ws;
    double* msum = (double*)ws;                                   // 8 doubles
    double* l1p  = (double*)(ws + 64);                            // NPART doubles
    double* l2p  = (double*)(ws + 64 + NPART * 8);
    double* l3p  = (double*)(ws + 64 + 2 * NPART * 8);
    size_t term_off = 64 + (size_t)3 * NPART * 8;                 // 196672
    float* term  = (float*)(ws + term_off);                       // B*N*4 floats
    int*   deg   = (int*)(ws + term_off + (size_t)B * N * 4 * 4); // B*N ints
    size_t zero_bytes = term_off + (size_t)B * N * 4 * 4 + (size_t)B * N * 4;

    hipMemsetAsync(d_ws, 0, zero_bytes, stream);

    dim3 mg(32, B);
    mean_kernel<<<mg, 256, 0, stream>>>(pred, msum, N);

    dim3 tg((T + 255) / 256, B);
    tetra_kernel<<<tg, 256, 0, stream>>>(pred, tetra, msum, term, deg,
                                         l2p, l3p, out, N, T, B);

    int BN = B * N;
    l1_kernel<<<(BN + 255) / 256, 256, 0, stream>>>(term, deg, l1p, BN);

    finalize_kernel<<<1, 256, 0, stream>>>(l1p, l2p, l3p, out,
                                           (double)BN * 4.0,
                                           (double)B * (double)T * 6.0);
}